// Round 1
// baseline (5170.937 us; speedup 1.0000x reference)
//
#include <hip/hip_runtime.h>

#define EPS 1e-6f

// ---------------------------------------------------------------------------
// Precompute G[k][h][n] = sum_d W2[MLP_IDX[k]][h][d] * fus_W1[k*128+d][n]
// Folds the ops-MLP second layer into the fusion first layer.
// grid 512 (= 8 k * 64 h), block 256 (= n)
// ---------------------------------------------------------------------------
__global__ void precompute_G(const float* __restrict__ ops_W2,
                             const float* __restrict__ fus_W1,
                             float* __restrict__ G) {
  int kh = blockIdx.x;            // 0..511
  int k = kh >> 6, h = kh & 63;
  int n = threadIdx.x;            // 0..255
  int op = (k < 4) ? k : ((k >> 1) + 2);   // MLP_IDX = {0,1,2,3,4,4,5,5}
  const float* w2row = ops_W2 + (op * 64 + h) * 128;
  const float* w1col = fus_W1 + (size_t)(k * 128) * 256 + n;
  float acc = 0.f;
#pragma unroll 8
  for (int d = 0; d < 128; ++d)
    acc = fmaf(w2row[d], w1col[(size_t)d * 256], acc);
  G[(size_t)kh * 256 + n] = acc;
}

// ---------------------------------------------------------------------------
// Precompute cbias[c][n] = fus_b1[n] + ptok[c] @ fus_W1[1024:1152, n]
//                        + sum_k ops_b2[MLP_IDX[k]] @ fus_W1[k*128:.., n]
// ptok has only 4 possible values (one-hot presence flags).
// grid 4 (= combo c), block 256 (= n)
// ---------------------------------------------------------------------------
__global__ void precompute_cbias(const float* __restrict__ pres_W1,
                                 const float* __restrict__ pres_b1,
                                 const float* __restrict__ pres_W2,
                                 const float* __restrict__ pres_b2,
                                 const float* __restrict__ fus_W1,
                                 const float* __restrict__ fus_b1,
                                 const float* __restrict__ ops_b2,
                                 float* __restrict__ cbias) {
  int c = blockIdx.x;   // 0..3
  int n = threadIdx.x;  // 0..255
  __shared__ float hrelu[64];
  if (threadIdx.x < 64)
    hrelu[threadIdx.x] =
        fmaxf(pres_W1[c * 64 + threadIdx.x] + pres_b1[threadIdx.x], 0.f);
  __syncthreads();
  float acc = fus_b1[n];
  for (int d = 0; d < 128; ++d) {
    float pt = pres_b2[d];
#pragma unroll 8
    for (int hh = 0; hh < 64; ++hh)
      pt = fmaf(hrelu[hh], pres_W2[hh * 128 + d], pt);
    acc = fmaf(pt, fus_W1[(size_t)(1024 + d) * 256 + n], acc);
  }
  // ops_b2 fold (zeros in setup, kept for generality)
  for (int k = 0; k < 8; ++k) {
    int op = (k < 4) ? k : ((k >> 1) + 2);
    for (int d = 0; d < 128; ++d)
      acc = fmaf(ops_b2[op * 128 + d], fus_W1[(size_t)(k * 128 + d) * 256 + n], acc);
  }
  cbias[c * 256 + n] = acc;
}

// ---------------------------------------------------------------------------
// Main fused kernel: 16 tokens per block, 256 threads (thread = tok*16 + l).
// Phases: load A/B + norms -> per-k feats + h GEMV -> folded fusion -> out.
// LDS 57.5 KB -> 2 blocks/CU.
// ---------------------------------------------------------------------------
__global__ __launch_bounds__(256, 2)
void drel_main(const float* __restrict__ x, const int* __restrict__ presence,
               const int* __restrict__ idx_i, const int* __restrict__ idx_j,
               const float* __restrict__ ops_W1, const float* __restrict__ ops_b1,
               const float* __restrict__ fus_W2, const float* __restrict__ fus_b2,
               const float* __restrict__ G, const float* __restrict__ cbias,
               float* __restrict__ out) {
  __shared__ float sAB[16][256];   // phases 1-2: A|B per token; phase 3+: hidden[256]
  __shared__ float sF[16][128];    // current feature vector per token
  __shared__ float sH[16][512];    // h_k for all 8 k (k*64 + c)
  __shared__ float sInvA[16], sInvB[16];
  __shared__ int sCombo[16];

  const int tid = threadIdx.x;
  const int tok = tid >> 4;   // 0..15
  const int l = tid & 15;     // 0..15

  const int blk = blockIdx.x;
  const int b = blk / 126;                 // 2016/16 = 126 blocks per batch row
  const int p = (blk % 126) * 16 + tok;    // pair index
  const int ii = idx_i[p];
  const int jj = idx_j[p];

  const float* Arow = x + (size_t)(b * 64 + ii) * 128;
  const float* Brow = x + (size_t)(b * 64 + jj) * 128;

  // ---- phase 1: load A/B (8 floats each per thread), squared norms ----
  float4 a0 = *(const float4*)(Arow + l * 8);
  float4 a1 = *(const float4*)(Arow + l * 8 + 4);
  float4 c0v = *(const float4*)(Brow + l * 8);
  float4 c1v = *(const float4*)(Brow + l * 8 + 4);
  *(float4*)(&sAB[tok][l * 8]) = a0;
  *(float4*)(&sAB[tok][l * 8 + 4]) = a1;
  *(float4*)(&sAB[tok][128 + l * 8]) = c0v;
  *(float4*)(&sAB[tok][128 + l * 8 + 4]) = c1v;

  float sa = a0.x * a0.x + a0.y * a0.y + a0.z * a0.z + a0.w * a0.w +
             a1.x * a1.x + a1.y * a1.y + a1.z * a1.z + a1.w * a1.w;
  float sb = c0v.x * c0v.x + c0v.y * c0v.y + c0v.z * c0v.z + c0v.w * c0v.w +
             c1v.x * c1v.x + c1v.y * c1v.y + c1v.z * c1v.z + c1v.w * c1v.w;
  // reduce across the 16 lanes of this token's group (16-aligned inside wave64)
  sa += __shfl_xor(sa, 1);  sb += __shfl_xor(sb, 1);
  sa += __shfl_xor(sa, 2);  sb += __shfl_xor(sb, 2);
  sa += __shfl_xor(sa, 4);  sb += __shfl_xor(sb, 4);
  sa += __shfl_xor(sa, 8);  sb += __shfl_xor(sb, 8);
  if (l == 0) {
    sInvA[tok] = 1.f / (sqrtf(sa) + EPS);
    sInvB[tok] = 1.f / (sqrtf(sb) + EPS);
    int pa = presence[b * 64 + ii];
    int pb = presence[b * 64 + jj];
    sCombo[tok] = pa ? (pb ? 0 : 1) : (pb ? 2 : 3);
  }
  __syncthreads();

  const float invA = sInvA[tok];
  const float invB = sInvB[tok];

  // ---- phase 2: for each feature k, build feat vec then h_k = relu(f@W1+b1) ----
  for (int k = 0; k < 8; ++k) {
#pragma unroll
    for (int q = 0; q < 8; ++q) {
      int d = l * 8 + q;
      float a = sAB[tok][d];
      float bb = sAB[tok][128 + d];
      float f;
      switch (k) {
        case 0: f = a * bb; break;
        case 1: f = a + bb; break;
        case 2: f = (a * invA) * (bb * invB); break;
        case 3: f = fabsf(a - bb); break;
        case 4: f = a - bb; break;
        case 5: f = bb - a; break;
        case 6: f = a / (bb + EPS); break;
        default: f = bb / (a + EPS); break;
      }
      sF[tok][d] = f;
    }
    __syncthreads();

    const int op = (k < 4) ? k : ((k >> 1) + 2);
    const float* W1 = ops_W1 + op * (128 * 64) + l * 4;
    float acc0 = 0.f, acc1 = 0.f, acc2 = 0.f, acc3 = 0.f;
#pragma unroll 8
    for (int d = 0; d < 128; ++d) {
      float f = sF[tok][d];
      float4 w = *(const float4*)(W1 + d * 64);
      acc0 = fmaf(f, w.x, acc0);
      acc1 = fmaf(f, w.y, acc1);
      acc2 = fmaf(f, w.z, acc2);
      acc3 = fmaf(f, w.w, acc3);
    }
    const float* b1p = ops_b1 + op * 64 + l * 4;
    sH[tok][k * 64 + l * 4 + 0] = fmaxf(acc0 + b1p[0], 0.f);
    sH[tok][k * 64 + l * 4 + 1] = fmaxf(acc1 + b1p[1], 0.f);
    sH[tok][k * 64 + l * 4 + 2] = fmaxf(acc2 + b1p[2], 0.f);
    sH[tok][k * 64 + l * 4 + 3] = fmaxf(acc3 + b1p[3], 0.f);
    __syncthreads();
  }

  // ---- phase 3: hidden = relu( H[512] @ G[512x256] + cbias[combo] ) ----
  const int combo = sCombo[tok];
  const int c0 = l * 16;
  float acc[16];
#pragma unroll
  for (int c = 0; c < 16; ++c) acc[c] = cbias[combo * 256 + c0 + c];
#pragma unroll 2
  for (int r = 0; r < 512; ++r) {
    float hv = sH[tok][r];
    const float* g = G + (size_t)r * 256 + c0;
    float4 g0 = *(const float4*)(g);
    float4 g1 = *(const float4*)(g + 4);
    float4 g2 = *(const float4*)(g + 8);
    float4 g3 = *(const float4*)(g + 12);
    acc[0]  = fmaf(hv, g0.x, acc[0]);  acc[1]  = fmaf(hv, g0.y, acc[1]);
    acc[2]  = fmaf(hv, g0.z, acc[2]);  acc[3]  = fmaf(hv, g0.w, acc[3]);
    acc[4]  = fmaf(hv, g1.x, acc[4]);  acc[5]  = fmaf(hv, g1.y, acc[5]);
    acc[6]  = fmaf(hv, g1.z, acc[6]);  acc[7]  = fmaf(hv, g1.w, acc[7]);
    acc[8]  = fmaf(hv, g2.x, acc[8]);  acc[9]  = fmaf(hv, g2.y, acc[9]);
    acc[10] = fmaf(hv, g2.z, acc[10]); acc[11] = fmaf(hv, g2.w, acc[11]);
    acc[12] = fmaf(hv, g3.x, acc[12]); acc[13] = fmaf(hv, g3.y, acc[13]);
    acc[14] = fmaf(hv, g3.z, acc[14]); acc[15] = fmaf(hv, g3.w, acc[15]);
  }
  // sAB's last read was before the final k-loop barrier -> safe to overwrite
#pragma unroll
  for (int c = 0; c < 16; ++c) sAB[tok][c0 + c] = fmaxf(acc[c], 0.f);
  __syncthreads();

  // ---- phase 4: out = hidden @ fus_W2 + fus_b2 ----
  const int o0 = l * 8;
  float o[8];
#pragma unroll
  for (int c = 0; c < 8; ++c) o[c] = fus_b2[o0 + c];
#pragma unroll 4
  for (int r = 0; r < 256; ++r) {
    float hv = sAB[tok][r];
    const float* w = fus_W2 + r * 128 + o0;
    float4 w0 = *(const float4*)(w);
    float4 w1 = *(const float4*)(w + 4);
    o[0] = fmaf(hv, w0.x, o[0]); o[1] = fmaf(hv, w0.y, o[1]);
    o[2] = fmaf(hv, w0.z, o[2]); o[3] = fmaf(hv, w0.w, o[3]);
    o[4] = fmaf(hv, w1.x, o[4]); o[5] = fmaf(hv, w1.y, o[5]);
    o[6] = fmaf(hv, w1.z, o[6]); o[7] = fmaf(hv, w1.w, o[7]);
  }
  float* outp = out + (size_t)(b * 2016 + p) * 128 + o0;
  *(float4*)(outp) = make_float4(o[0], o[1], o[2], o[3]);
  *(float4*)(outp + 4) = make_float4(o[4], o[5], o[6], o[7]);
}

// ---------------------------------------------------------------------------
extern "C" void kernel_launch(void* const* d_in, const int* in_sizes, int n_in,
                              void* d_out, int out_size, void* d_ws, size_t ws_size,
                              hipStream_t stream) {
  const float* x        = (const float*)d_in[0];
  const int*   presence = (const int*)d_in[1];
  const int*   idx_i    = (const int*)d_in[2];
  const int*   idx_j    = (const int*)d_in[3];
  const float* ops_W1   = (const float*)d_in[4];
  const float* ops_b1   = (const float*)d_in[5];
  const float* ops_W2   = (const float*)d_in[6];
  const float* ops_b2   = (const float*)d_in[7];
  const float* pres_W1  = (const float*)d_in[8];
  const float* pres_b1  = (const float*)d_in[9];
  const float* pres_W2  = (const float*)d_in[10];
  const float* pres_b2  = (const float*)d_in[11];
  const float* fus_W1   = (const float*)d_in[12];
  const float* fus_b1   = (const float*)d_in[13];
  const float* fus_W2   = (const float*)d_in[14];
  const float* fus_b2   = (const float*)d_in[15];

  float* G = (float*)d_ws;                 // 512*256 floats = 512 KB
  float* cbias = G + 512 * 256;            // 4*256 floats

  precompute_G<<<512, 256, 0, stream>>>(ops_W2, fus_W1, G);
  precompute_cbias<<<4, 256, 0, stream>>>(pres_W1, pres_b1, pres_W2, pres_b2,
                                          fus_W1, fus_b1, ops_b2, cbias);
  // 64 batches * 126 blocks = 8064 blocks, 16 tokens each = 129024 tokens
  drel_main<<<8064, 256, 0, stream>>>(x, presence, idx_i, idx_j, ops_W1, ops_b1,
                                      fus_W2, fus_b2, G, cbias, (float*)d_out);
}

// Round 2
// 539.749 us; speedup vs baseline: 9.5803x; 9.5803x over previous
//
#include <hip/hip_runtime.h>

#define EPS 1e-6f

using bfrag = __attribute__((ext_vector_type(8))) short;   // 8 bf16
using ffrag = __attribute__((ext_vector_type(4))) float;   // C/D frag

#define MFMA(a, b, c) __builtin_amdgcn_mfma_f32_16x16x32_bf16((a), (b), (c), 0, 0, 0)

__device__ __host__ __forceinline__ unsigned short bf_hi(float x) {
  unsigned u = __builtin_bit_cast(unsigned, x);
  return (unsigned short)((u + 0x7FFFu + ((u >> 16) & 1u)) >> 16);
}
__device__ __forceinline__ float bf_f(unsigned short h) {
  unsigned u = (unsigned)h << 16;
  return __builtin_bit_cast(float, u);
}
__device__ __forceinline__ int op_of(int k) { return (k < 4) ? k : ((k >> 1) + 2); }

// ---------------------------------------------------------------------------
// ws layout (bytes):
//   GpH 0..256K | GpL 256K..512K | W1H 512K..640K | W1L 640K..768K
//   W2H 768K..832K | W2L 832K..896K | cbias 896K..900K
// Packed B-fragment order for W[K x N], tile nt (16 cols), kstep kk (32 rows):
//   elem j of lane L = W[kk*32 + (L>>4)*8 + j][nt*16 + (L&15)]
//   flat: ((nt_total_idx*ksteps + kk)*64 + L)*8 + j
// ---------------------------------------------------------------------------

// G[r][n] = sum_d ops_W2[op(k)][h][d] * fus_W1[k*128+d][n], r = k*64+h.
// grid 512 x 256 threads, one element each; writes split hi/lo packed.
__global__ void pack_G(const float* __restrict__ ops_W2,
                       const float* __restrict__ fus_W1,
                       unsigned short* __restrict__ GpH,
                       unsigned short* __restrict__ GpL) {
  int gid = blockIdx.x * 256 + threadIdx.x;   // 0..131071
  int r = gid >> 8, n = gid & 255;
  int k = r >> 6, h = r & 63;
  int op = op_of(k);
  const float* w2 = ops_W2 + (size_t)(op * 64 + h) * 128;
  const float* w1 = fus_W1 + (size_t)(k * 128) * 256 + n;
  float acc = 0.f;
#pragma unroll 8
  for (int d = 0; d < 128; ++d) acc = fmaf(w2[d], w1[(size_t)d * 256], acc);
  int nt = n >> 4, kk = r >> 5, quad = (r >> 3) & 3, j = r & 7;
  int lane = quad * 16 + (n & 15);
  size_t pos = ((size_t)(nt * 16 + kk) * 64 + lane) * 8 + j;
  unsigned short hi = bf_hi(acc);
  GpH[pos] = hi;
  GpL[pos] = bf_hi(acc - bf_f(hi));
}

// ops_W1: [6][128][64] -> packed [op 8][nt 4][kk 4][lane 64][j 8], grid 32x256
__global__ void pack_W1(const float* __restrict__ ops_W1,
                        unsigned short* __restrict__ W1H,
                        unsigned short* __restrict__ W1L) {
  int gid = blockIdx.x * 256 + threadIdx.x;   // 0..8191
  int lane = gid & 63, kk = (gid >> 6) & 3, nt = (gid >> 8) & 3, k = gid >> 10;
  int op = op_of(k);
  int col = nt * 16 + (lane & 15);
#pragma unroll
  for (int j = 0; j < 8; ++j) {
    int d = kk * 32 + ((lane >> 4) & 3) * 8 + j;
    float w = ops_W1[((size_t)op * 128 + d) * 64 + col];
    unsigned short hi = bf_hi(w);
    W1H[(size_t)gid * 8 + j] = hi;
    W1L[(size_t)gid * 8 + j] = bf_hi(w - bf_f(hi));
  }
}

// fus_W2: [256][128] -> packed [nt 8][kk 8][lane 64][j 8], grid 16x256
__global__ void pack_W2f(const float* __restrict__ fus_W2,
                         unsigned short* __restrict__ W2H,
                         unsigned short* __restrict__ W2L) {
  int gid = blockIdx.x * 256 + threadIdx.x;   // 0..4095
  int lane = gid & 63, kk = (gid >> 6) & 7, nt = gid >> 9;
  int col = nt * 16 + (lane & 15);
#pragma unroll
  for (int j = 0; j < 8; ++j) {
    int d = kk * 32 + ((lane >> 4) & 3) * 8 + j;
    float w = fus_W2[(size_t)d * 128 + col];
    unsigned short hi = bf_hi(w);
    W2H[(size_t)gid * 8 + j] = hi;
    W2L[(size_t)gid * 8 + j] = bf_hi(w - bf_f(hi));
  }
}

// cbias[c][n] (fp32): fus_b1 + ptok(c) @ fus_W1[1024:1152] + ops_b2 fold
__global__ void precompute_cbias(const float* __restrict__ pres_W1,
                                 const float* __restrict__ pres_b1,
                                 const float* __restrict__ pres_W2,
                                 const float* __restrict__ pres_b2,
                                 const float* __restrict__ fus_W1,
                                 const float* __restrict__ fus_b1,
                                 const float* __restrict__ ops_b2,
                                 float* __restrict__ cbias) {
  int c = blockIdx.x, n = threadIdx.x;
  __shared__ float hrelu[64];
  if (threadIdx.x < 64)
    hrelu[threadIdx.x] =
        fmaxf(pres_W1[c * 64 + threadIdx.x] + pres_b1[threadIdx.x], 0.f);
  __syncthreads();
  float acc = fus_b1[n];
  for (int d = 0; d < 128; ++d) {
    float pt = pres_b2[d];
#pragma unroll 8
    for (int hh = 0; hh < 64; ++hh)
      pt = fmaf(hrelu[hh], pres_W2[hh * 128 + d], pt);
    acc = fmaf(pt, fus_W1[(size_t)(1024 + d) * 256 + n], acc);
  }
  for (int k = 0; k < 8; ++k) {
    int op = op_of(k);
    for (int d = 0; d < 128; ++d)
      acc = fmaf(ops_b2[op * 128 + d], fus_W1[(size_t)(k * 128 + d) * 256 + n], acc);
  }
  cbias[c * 256 + n] = acc;
}

// ---------------------------------------------------------------------------
// Main kernel: 16 tokens/block, 256 threads = 4 waves.
// All GEMMs as 16x16x32 bf16 MFMA with split-bf16 (3 MFMAs per product).
// LDS (50.2 KB): F hi/lo [16][136] (aliased by Hid hi/lo [16][264]) +
//                H hi/lo [16][520] + combo[16].
// Row strides stagger banks by 4 dwords/row -> 2-way max (free).
// ---------------------------------------------------------------------------
__global__ __launch_bounds__(256, 3)
void drel_main(const float* __restrict__ x, const int* __restrict__ presence,
               const int* __restrict__ idx_i, const int* __restrict__ idx_j,
               const float* __restrict__ ops_b1, const float* __restrict__ fus_b2,
               const unsigned short* __restrict__ W1H, const unsigned short* __restrict__ W1L,
               const unsigned short* __restrict__ GpH, const unsigned short* __restrict__ GpL,
               const unsigned short* __restrict__ W2H, const unsigned short* __restrict__ W2L,
               const float* __restrict__ cbias, float* __restrict__ out) {
  __shared__ __align__(16) char smem[50240];
  unsigned short (*Fh)[136] = reinterpret_cast<unsigned short(*)[136]>(smem);
  unsigned short (*Fl)[136] = reinterpret_cast<unsigned short(*)[136]>(smem + 4352);
  unsigned short (*Dh)[264] = reinterpret_cast<unsigned short(*)[264]>(smem);        // aliases F
  unsigned short (*Dl)[264] = reinterpret_cast<unsigned short(*)[264]>(smem + 8448); // aliases F
  unsigned short (*Hh)[520] = reinterpret_cast<unsigned short(*)[520]>(smem + 16896);
  unsigned short (*Hl)[520] = reinterpret_cast<unsigned short(*)[520]>(smem + 33536);
  int* sCombo = reinterpret_cast<int*>(smem + 50176);

  const int tid = threadIdx.x;
  const int wv = tid >> 6;          // wave 0..3
  const int lane = tid & 63;
  const int quad = lane >> 4;
  const int c0 = lane & 15;
  const int t = tid >> 4;           // token 0..15
  const int l = tid & 15;           // lane-in-token

  const int blk = blockIdx.x;
  const int b = blk / 126;
  const int p0 = (blk % 126) * 16;
  const int p = p0 + t;
  const int ii = idx_i[p], jj = idx_j[p];

  // ---- phase 1: A/B rows into registers, norms via 16-lane butterfly ----
  const float* Ar = x + (size_t)(b * 64 + ii) * 128 + l * 8;
  const float* Br = x + (size_t)(b * 64 + jj) * 128 + l * 8;
  float4 a0 = *(const float4*)Ar, a1 = *(const float4*)(Ar + 4);
  float4 b0 = *(const float4*)Br, b1v = *(const float4*)(Br + 4);
  float af[8] = {a0.x, a0.y, a0.z, a0.w, a1.x, a1.y, a1.z, a1.w};
  float bf[8] = {b0.x, b0.y, b0.z, b0.w, b1v.x, b1v.y, b1v.z, b1v.w};

  float sa = 0.f, sb = 0.f;
#pragma unroll
  for (int q = 0; q < 8; ++q) { sa = fmaf(af[q], af[q], sa); sb = fmaf(bf[q], bf[q], sb); }
#pragma unroll
  for (int m = 1; m < 16; m <<= 1) { sa += __shfl_xor(sa, m); sb += __shfl_xor(sb, m); }
  const float invA = 1.f / (sqrtf(sa) + EPS);
  const float invB = 1.f / (sqrtf(sb) + EPS);
  if (l == 0) {
    int pa = presence[b * 64 + ii], pb = presence[b * 64 + jj];
    sCombo[t] = pa ? (pb ? 0 : 1) : (pb ? 2 : 3);
  }

  // ---- phase 2: per op k: feats -> split bf16 LDS -> MFMA -> H hi/lo ----
  for (int k = 0; k < 8; ++k) {
    bfrag vh, vl;
#pragma unroll
    for (int q = 0; q < 8; ++q) {
      float a = af[q], bb = bf[q], f;
      switch (k) {
        case 0: f = a * bb; break;
        case 1: f = a + bb; break;
        case 2: f = (a * invA) * (bb * invB); break;
        case 3: f = fabsf(a - bb); break;
        case 4: f = a - bb; break;
        case 5: f = bb - a; break;
        case 6: f = a / (bb + EPS); break;
        default: f = bb / (a + EPS); break;
      }
      unsigned short hi = bf_hi(f);
      vh[q] = (short)hi;
      vl[q] = (short)bf_hi(f - bf_f(hi));
    }
    *(bfrag*)&Fh[t][l * 8] = vh;
    *(bfrag*)&Fl[t][l * 8] = vl;
    __syncthreads();

    bfrag ah[4], al[4];
#pragma unroll
    for (int kk = 0; kk < 4; ++kk) {
      ah[kk] = *(const bfrag*)&Fh[c0][kk * 32 + quad * 8];
      al[kk] = *(const bfrag*)&Fl[c0][kk * 32 + quad * 8];
    }
    const unsigned short* bph = W1H + (size_t)((k * 4 + wv) * 4) * 512 + lane * 8;
    const unsigned short* bpl = W1L + (size_t)((k * 4 + wv) * 4) * 512 + lane * 8;
    ffrag t1 = {0.f, 0.f, 0.f, 0.f}, t2 = t1, t3 = t1;
#pragma unroll
    for (int kk = 0; kk < 4; ++kk) {
      bfrag bh = *(const bfrag*)(bph + kk * 512);
      bfrag bl = *(const bfrag*)(bpl + kk * 512);
      t1 = MFMA(ah[kk], bh, t1);
      t2 = MFMA(ah[kk], bl, t2);
      t3 = MFMA(al[kk], bh, t3);
    }
    __syncthreads();  // F reads done -> next iter may overwrite F

    const int hcol = k * 64 + wv * 16 + c0;
    const float bb1 = ops_b1[op_of(k) * 64 + wv * 16 + c0];
#pragma unroll
    for (int i = 0; i < 4; ++i) {
      float v = fmaxf(t1[i] + t2[i] + t3[i] + bb1, 0.f);
      unsigned short hi = bf_hi(v);
      Hh[quad * 4 + i][hcol] = hi;
      Hl[quad * 4 + i][hcol] = bf_hi(v - bf_f(hi));
    }
  }
  __syncthreads();  // H complete; F region free for Hid

  // ---- phase 3: Hid[16x256] = relu(H[16x512] @ G + cbias[combo]) ----
  int combos[4];
#pragma unroll
  for (int i = 0; i < 4; ++i) combos[i] = sCombo[quad * 4 + i];

  ffrag u1[4], u2[4];
#pragma unroll
  for (int nt4 = 0; nt4 < 4; ++nt4) {
    int col = (wv * 4 + nt4) * 16 + c0;
#pragma unroll
    for (int i = 0; i < 4; ++i) u1[nt4][i] = cbias[combos[i] * 256 + col];
    u2[nt4] = ffrag{0.f, 0.f, 0.f, 0.f};
  }
#pragma unroll 4
  for (int kk = 0; kk < 16; ++kk) {
    bfrag ah = *(const bfrag*)&Hh[c0][kk * 32 + quad * 8];
    bfrag al = *(const bfrag*)&Hl[c0][kk * 32 + quad * 8];
#pragma unroll
    for (int nt4 = 0; nt4 < 4; ++nt4) {
      size_t pos = ((size_t)((wv * 4 + nt4) * 16 + kk) * 64 + lane) * 8;
      bfrag bh = *(const bfrag*)(GpH + pos);
      bfrag bl = *(const bfrag*)(GpL + pos);
      u1[nt4] = MFMA(ah, bh, u1[nt4]);
      u2[nt4] = MFMA(ah, bl, u2[nt4]);
      u2[nt4] = MFMA(al, bh, u2[nt4]);
    }
  }
#pragma unroll
  for (int nt4 = 0; nt4 < 4; ++nt4) {
    int col = (wv * 4 + nt4) * 16 + c0;
#pragma unroll
    for (int i = 0; i < 4; ++i) {
      float v = fmaxf(u1[nt4][i] + u2[nt4][i], 0.f);
      unsigned short hi = bf_hi(v);
      Dh[quad * 4 + i][col] = hi;
      Dl[quad * 4 + i][col] = bf_hi(v - bf_f(hi));
    }
  }
  __syncthreads();

  // ---- phase 4: out = Hid @ fus_W2 + fus_b2 ----
  ffrag o1[2], o2[2];
#pragma unroll
  for (int nt2 = 0; nt2 < 2; ++nt2) {
    int col = (wv * 2 + nt2) * 16 + c0;
    float bias = fus_b2[col];
    o1[nt2] = ffrag{bias, bias, bias, bias};
    o2[nt2] = ffrag{0.f, 0.f, 0.f, 0.f};
  }
#pragma unroll
  for (int kk = 0; kk < 8; ++kk) {
    bfrag ah = *(const bfrag*)&Dh[c0][kk * 32 + quad * 8];
    bfrag al = *(const bfrag*)&Dl[c0][kk * 32 + quad * 8];
#pragma unroll
    for (int nt2 = 0; nt2 < 2; ++nt2) {
      size_t pos = ((size_t)((wv * 2 + nt2) * 8 + kk) * 64 + lane) * 8;
      bfrag bh = *(const bfrag*)(W2H + pos);
      bfrag bl = *(const bfrag*)(W2L + pos);
      o1[nt2] = MFMA(ah, bh, o1[nt2]);
      o2[nt2] = MFMA(ah, bl, o2[nt2]);
      o2[nt2] = MFMA(al, bh, o2[nt2]);
    }
  }
#pragma unroll
  for (int nt2 = 0; nt2 < 2; ++nt2) {
    int col = (wv * 2 + nt2) * 16 + c0;
#pragma unroll
    for (int i = 0; i < 4; ++i) {
      int row = quad * 4 + i;
      out[(size_t)(b * 2016 + p0 + row) * 128 + col] = o1[nt2][i] + o2[nt2][i];
    }
  }
}

// ---------------------------------------------------------------------------
extern "C" void kernel_launch(void* const* d_in, const int* in_sizes, int n_in,
                              void* d_out, int out_size, void* d_ws, size_t ws_size,
                              hipStream_t stream) {
  const float* x        = (const float*)d_in[0];
  const int*   presence = (const int*)d_in[1];
  const int*   idx_i    = (const int*)d_in[2];
  const int*   idx_j    = (const int*)d_in[3];
  const float* ops_W1   = (const float*)d_in[4];
  const float* ops_b1   = (const float*)d_in[5];
  const float* ops_W2   = (const float*)d_in[6];
  const float* ops_b2   = (const float*)d_in[7];
  const float* pres_W1  = (const float*)d_in[8];
  const float* pres_b1  = (const float*)d_in[9];
  const float* pres_W2  = (const float*)d_in[10];
  const float* pres_b2  = (const float*)d_in[11];
  const float* fus_W1   = (const float*)d_in[12];
  const float* fus_b1   = (const float*)d_in[13];
  const float* fus_W2   = (const float*)d_in[14];
  const float* fus_b2   = (const float*)d_in[15];

  char* ws = (char*)d_ws;
  unsigned short* GpH = (unsigned short*)(ws);
  unsigned short* GpL = (unsigned short*)(ws + 262144);
  unsigned short* W1H = (unsigned short*)(ws + 524288);
  unsigned short* W1L = (unsigned short*)(ws + 655360);
  unsigned short* W2H = (unsigned short*)(ws + 786432);
  unsigned short* W2L = (unsigned short*)(ws + 851968);
  float*          CB  = (float*)(ws + 917504);

  pack_G<<<512, 256, 0, stream>>>(ops_W2, fus_W1, GpH, GpL);
  pack_W1<<<32, 256, 0, stream>>>(ops_W1, W1H, W1L);
  pack_W2f<<<16, 256, 0, stream>>>(fus_W2, W2H, W2L);
  precompute_cbias<<<4, 256, 0, stream>>>(pres_W1, pres_b1, pres_W2, pres_b2,
                                          fus_W1, fus_b1, ops_b2, CB);

  drel_main<<<8064, 256, 0, stream>>>(x, presence, idx_i, idx_j, ops_b1, fus_b2,
                                      W1H, W1L, GpH, GpL, W2H, W2L, CB,
                                      (float*)d_out);
}

// Round 3
// 390.052 us; speedup vs baseline: 13.2570x; 1.3838x over previous
//
#include <hip/hip_runtime.h>

#define EPS 1e-6f

using bfrag = __attribute__((ext_vector_type(8))) short;   // 8 bf16
using ffrag = __attribute__((ext_vector_type(4))) float;   // C/D frag

#define MFMA(a, b, c) __builtin_amdgcn_mfma_f32_16x16x32_bf16((a), (b), (c), 0, 0, 0)

__device__ __forceinline__ unsigned short bf_hi(float x) {
  unsigned u = __builtin_bit_cast(unsigned, x);
  return (unsigned short)((u + 0x7FFFu + ((u >> 16) & 1u)) >> 16);
}
__device__ __forceinline__ float bf_f(unsigned short h) {
  unsigned u = (unsigned)h << 16;
  return __builtin_bit_cast(float, u);
}
__device__ __forceinline__ void split_bf(float f, short& h, short& l) {
  unsigned short hi = bf_hi(f);
  h = (short)hi;
  l = (short)bf_hi(f - bf_f(hi));
}
__device__ __forceinline__ int op_of(int k) { return (k < 4) ? k : ((k >> 1) + 2); }

// ---------------------------------------------------------------------------
// ws layout (bytes):
//   GpH 0..256K | GpL 256K..512K | W1H 512K..640K | W1L 640K..768K
//   W2H 768K..832K | W2L 832K..896K | cbias 896K..900K
// Packed B-fragment order for W[K x N]: elem j of lane L =
//   W[kk*32 + (L>>4)*8 + j][nt*16 + (L&15)], flat ((ntIdx*ksteps+kk)*64+L)*8+j
// ---------------------------------------------------------------------------
// ONE prologue kernel, block-specialized:
//   blocks 0..511   : pack G  (fold ops_W2 into fus_W1)
//   blocks 512..543 : pack ops_W1
//   blocks 544..559 : pack fus_W2
//   blocks 560..563 : cbias (4 presence combos)
__global__ void prologue(const float* __restrict__ ops_W1,
                         const float* __restrict__ ops_W2,
                         const float* __restrict__ ops_b2,
                         const float* __restrict__ pres_W1,
                         const float* __restrict__ pres_b1,
                         const float* __restrict__ pres_W2,
                         const float* __restrict__ pres_b2,
                         const float* __restrict__ fus_W1,
                         const float* __restrict__ fus_b1,
                         const float* __restrict__ fus_W2,
                         unsigned short* __restrict__ GpH,
                         unsigned short* __restrict__ GpL,
                         unsigned short* __restrict__ W1H,
                         unsigned short* __restrict__ W1L,
                         unsigned short* __restrict__ W2H,
                         unsigned short* __restrict__ W2L,
                         float* __restrict__ cb) {
  const int blk = blockIdx.x;
  const int tid = threadIdx.x;

  if (blk < 512) {
    // ---- pack_G: G[r][n] = sum_d ops_W2[op(k)][h][d] * fus_W1[k*128+d][n]
    int r = blk, n = tid;
    int k = r >> 6, h = r & 63;
    int op = op_of(k);
    const float* w2 = ops_W2 + (size_t)(op * 64 + h) * 128;
    const float* w1 = fus_W1 + (size_t)(k * 128) * 256 + n;
    float a0 = 0.f, a1 = 0.f, a2 = 0.f, a3 = 0.f;
#pragma unroll 8
    for (int d = 0; d < 128; d += 4) {
      a0 = fmaf(w2[d], w1[(size_t)d * 256], a0);
      a1 = fmaf(w2[d + 1], w1[(size_t)(d + 1) * 256], a1);
      a2 = fmaf(w2[d + 2], w1[(size_t)(d + 2) * 256], a2);
      a3 = fmaf(w2[d + 3], w1[(size_t)(d + 3) * 256], a3);
    }
    float acc = (a0 + a1) + (a2 + a3);
    int nt = n >> 4, kk = r >> 5, quad = (r >> 3) & 3, j = r & 7;
    int lane = quad * 16 + (n & 15);
    int pos = ((nt * 16 + kk) * 64 + lane) * 8 + j;
    short hh, ll;
    split_bf(acc, hh, ll);
    GpH[pos] = (unsigned short)hh;
    GpL[pos] = (unsigned short)ll;
  } else if (blk < 544) {
    // ---- pack_W1: [op 8][nt 4][kk 4][lane 64][j 8]
    int gid = (blk - 512) * 256 + tid;   // 0..8191
    int lane = gid & 63, kk = (gid >> 6) & 3, nt = (gid >> 8) & 3, k = gid >> 10;
    int op = op_of(k);
    int col = nt * 16 + (lane & 15);
#pragma unroll
    for (int j = 0; j < 8; ++j) {
      int d = kk * 32 + ((lane >> 4) & 3) * 8 + j;
      short hh, ll;
      split_bf(ops_W1[((size_t)op * 128 + d) * 64 + col], hh, ll);
      W1H[gid * 8 + j] = (unsigned short)hh;
      W1L[gid * 8 + j] = (unsigned short)ll;
    }
  } else if (blk < 560) {
    // ---- pack_W2f: [nt 8][kk 8][lane 64][j 8]
    int gid = (blk - 544) * 256 + tid;   // 0..4095
    int lane = gid & 63, kk = (gid >> 6) & 7, nt = gid >> 9;
    int col = nt * 16 + (lane & 15);
#pragma unroll
    for (int j = 0; j < 8; ++j) {
      int d = kk * 32 + ((lane >> 4) & 3) * 8 + j;
      short hh, ll;
      split_bf(fus_W2[(size_t)d * 128 + col], hh, ll);
      W2H[gid * 8 + j] = (unsigned short)hh;
      W2L[gid * 8 + j] = (unsigned short)ll;
    }
  } else {
    // ---- cbias[c][n]
    int c = blk - 560, n = tid;
    __shared__ float hrelu[64];
    __shared__ float ptok[128];
    if (n < 64) hrelu[n] = fmaxf(pres_W1[c * 64 + n] + pres_b1[n], 0.f);
    __syncthreads();
    if (n < 128) {
      float p0 = pres_b2[n], p1 = 0.f;
#pragma unroll 8
      for (int hh = 0; hh < 64; hh += 2) {
        p0 = fmaf(hrelu[hh], pres_W2[hh * 128 + n], p0);
        p1 = fmaf(hrelu[hh + 1], pres_W2[(hh + 1) * 128 + n], p1);
      }
      ptok[n] = p0 + p1;
    }
    __syncthreads();
    float acc = fus_b1[n];
#pragma unroll 4
    for (int d = 0; d < 128; ++d)
      acc = fmaf(ptok[d], fus_W1[(size_t)(1024 + d) * 256 + n], acc);
    float acc2 = 0.f;  // ops_b2 fold (zeros in setup, kept for generality)
    for (int k = 0; k < 8; ++k) {
      int op = op_of(k);
#pragma unroll 4
      for (int d = 0; d < 128; ++d)
        acc2 = fmaf(ops_b2[op * 128 + d], fus_W1[(size_t)(k * 128 + d) * 256 + n], acc2);
    }
    cb[c * 256 + n] = acc + acc2;
  }
}

// ---------------------------------------------------------------------------
// Main kernel: 32 tokens/block (two 16-row M-tiles), 256 threads = 4 waves.
// Each B-fragment load feeds BOTH M-tiles -> weight L2 traffic halved.
// Split-K: H built & consumed in two 256-col rounds (halves H LDS).
// k=5 feature = -(k=4) with identical op-4 MLP -> derived, GEMV skipped.
// LDS 67.7 KB -> 2 blocks/CU.
// ---------------------------------------------------------------------------
__device__ __forceinline__ void ld8(const float* p, float* r) {
  float4 t0 = *(const float4*)p, t1 = *(const float4*)(p + 4);
  r[0] = t0.x; r[1] = t0.y; r[2] = t0.z; r[3] = t0.w;
  r[4] = t1.x; r[5] = t1.y; r[6] = t1.z; r[7] = t1.w;
}

template <int K, int KB, bool NEG5>
__device__ __forceinline__ void phase2_op(
    int t, int l, int wv, int lane, int quad, int c0,
    const float (&af0)[8], const float (&bf0)[8],
    const float (&af1)[8], const float (&bf1)[8],
    float invA0, float invB0, float invA1, float invB1,
    const float (&ra0)[8], const float (&rb0)[8],
    const float (&ra1)[8], const float (&rb1)[8],
    unsigned short (*Fh)[136], unsigned short (*Fl)[136],
    unsigned short (*Hh)[264], unsigned short (*Hl)[264],
    const unsigned short* __restrict__ W1H,
    const unsigned short* __restrict__ W1L,
    const float* __restrict__ ops_b1) {
  bfrag vh0, vl0, vh1, vl1;
#pragma unroll
  for (int q = 0; q < 8; ++q) {
    float f0, f1;
    if constexpr (K == 0)      { f0 = af0[q] * bf0[q];            f1 = af1[q] * bf1[q]; }
    else if constexpr (K == 1) { f0 = af0[q] + bf0[q];            f1 = af1[q] + bf1[q]; }
    else if constexpr (K == 2) { f0 = (af0[q] * invA0) * (bf0[q] * invB0);
                                 f1 = (af1[q] * invA1) * (bf1[q] * invB1); }
    else if constexpr (K == 3) { f0 = fabsf(af0[q] - bf0[q]);     f1 = fabsf(af1[q] - bf1[q]); }
    else if constexpr (K == 4) { f0 = af0[q] - bf0[q];            f1 = af1[q] - bf1[q]; }
    else if constexpr (K == 6) { f0 = af0[q] * rb0[q];            f1 = af1[q] * rb1[q]; }
    else                       { f0 = bf0[q] * ra0[q];            f1 = bf1[q] * ra1[q]; }
    short h0, l0, h1, l1;
    split_bf(f0, h0, l0); split_bf(f1, h1, l1);
    vh0[q] = h0; vl0[q] = l0; vh1[q] = h1; vl1[q] = l1;
  }
  *(bfrag*)&Fh[t][l * 8] = vh0;      *(bfrag*)&Fl[t][l * 8] = vl0;
  *(bfrag*)&Fh[16 + t][l * 8] = vh1; *(bfrag*)&Fl[16 + t][l * 8] = vl1;
  __syncthreads();

  constexpr int OP = (K < 4) ? K : ((K >> 1) + 2);
  const int wbase = ((K * 4 + wv) * 4) * 512 + lane * 8;
  ffrag s1_0 = {0.f, 0.f, 0.f, 0.f}, s2_0 = s1_0, s3_0 = s1_0;
  ffrag s1_1 = s1_0, s2_1 = s1_0, s3_1 = s1_0;
#pragma unroll
  for (int kk = 0; kk < 4; ++kk) {
    bfrag bh = *(const bfrag*)(W1H + wbase + kk * 512);
    bfrag bl = *(const bfrag*)(W1L + wbase + kk * 512);
    bfrag ah0 = *(const bfrag*)&Fh[c0][kk * 32 + quad * 8];
    bfrag al0 = *(const bfrag*)&Fl[c0][kk * 32 + quad * 8];
    bfrag ah1 = *(const bfrag*)&Fh[16 + c0][kk * 32 + quad * 8];
    bfrag al1 = *(const bfrag*)&Fl[16 + c0][kk * 32 + quad * 8];
    s1_0 = MFMA(ah0, bh, s1_0); s2_0 = MFMA(ah0, bl, s2_0); s3_0 = MFMA(al0, bh, s3_0);
    s1_1 = MFMA(ah1, bh, s1_1); s2_1 = MFMA(ah1, bl, s2_1); s3_1 = MFMA(al1, bh, s3_1);
  }
  __syncthreads();   // F reads done -> next op may overwrite F

  const float bb1 = ops_b1[OP * 64 + wv * 16 + c0];
  const int col = KB * 64 + wv * 16 + c0;
#pragma unroll
  for (int i = 0; i < 4; ++i) {
    float v0 = s1_0[i] + s2_0[i] + s3_0[i];
    float v1 = s1_1[i] + s2_1[i] + s3_1[i];
    short h, lo;
    split_bf(fmaxf(v0 + bb1, 0.f), h, lo);
    Hh[quad * 4 + i][col] = (unsigned short)h; Hl[quad * 4 + i][col] = (unsigned short)lo;
    split_bf(fmaxf(v1 + bb1, 0.f), h, lo);
    Hh[16 + quad * 4 + i][col] = (unsigned short)h; Hl[16 + quad * 4 + i][col] = (unsigned short)lo;
    if constexpr (NEG5) {   // k=5: feature = -f4, same op-4 W1/b1
      split_bf(fmaxf(-v0 + bb1, 0.f), h, lo);
      Hh[quad * 4 + i][col + 64] = (unsigned short)h; Hl[quad * 4 + i][col + 64] = (unsigned short)lo;
      split_bf(fmaxf(-v1 + bb1, 0.f), h, lo);
      Hh[16 + quad * 4 + i][col + 64] = (unsigned short)h; Hl[16 + quad * 4 + i][col + 64] = (unsigned short)lo;
    }
  }
}

__device__ __forceinline__ void phase3_round(
    int r, int wv, int lane, int quad, int c0,
    unsigned short (*Hh)[264], unsigned short (*Hl)[264],
    const unsigned short* __restrict__ GpH, const unsigned short* __restrict__ GpL,
    ffrag (&u1)[4], ffrag (&u2)[4], ffrag (&v1)[4], ffrag (&v2)[4]) {
#pragma unroll
  for (int kk = 0; kk < 8; ++kk) {
    bfrag ah0 = *(const bfrag*)&Hh[c0][kk * 32 + quad * 8];
    bfrag al0 = *(const bfrag*)&Hl[c0][kk * 32 + quad * 8];
    bfrag ah1 = *(const bfrag*)&Hh[16 + c0][kk * 32 + quad * 8];
    bfrag al1 = *(const bfrag*)&Hl[16 + c0][kk * 32 + quad * 8];
#pragma unroll
    for (int nt4 = 0; nt4 < 4; ++nt4) {
      int off = (((wv * 4 + nt4) * 16 + r * 8 + kk) * 64 + lane) * 8;
      bfrag bh = *(const bfrag*)(GpH + off);
      bfrag bl = *(const bfrag*)(GpL + off);
      u1[nt4] = MFMA(ah0, bh, u1[nt4]);
      u2[nt4] = MFMA(ah0, bl, u2[nt4]);
      u2[nt4] = MFMA(al0, bh, u2[nt4]);
      v1[nt4] = MFMA(ah1, bh, v1[nt4]);
      v2[nt4] = MFMA(ah1, bl, v2[nt4]);
      v2[nt4] = MFMA(al1, bh, v2[nt4]);
    }
  }
}

__global__ __launch_bounds__(256, 2)
void drel_main(const float* __restrict__ x, const int* __restrict__ presence,
               const int* __restrict__ idx_i, const int* __restrict__ idx_j,
               const float* __restrict__ ops_b1, const float* __restrict__ fus_b2,
               const unsigned short* __restrict__ W1H, const unsigned short* __restrict__ W1L,
               const unsigned short* __restrict__ GpH, const unsigned short* __restrict__ GpL,
               const unsigned short* __restrict__ W2H, const unsigned short* __restrict__ W2L,
               const float* __restrict__ cbias, float* __restrict__ out) {
  __shared__ __align__(16) char smem[67712];
  unsigned short (*Fh)[136] = reinterpret_cast<unsigned short(*)[136]>(smem);
  unsigned short (*Fl)[136] = reinterpret_cast<unsigned short(*)[136]>(smem + 8704);
  unsigned short (*Dh)[264] = reinterpret_cast<unsigned short(*)[264]>(smem);          // alias F
  unsigned short (*Dl)[264] = reinterpret_cast<unsigned short(*)[264]>(smem + 16896);  // alias F
  unsigned short (*Hh)[264] = reinterpret_cast<unsigned short(*)[264]>(smem + 33792);
  unsigned short (*Hl)[264] = reinterpret_cast<unsigned short(*)[264]>(smem + 50688);
  int* sCombo = reinterpret_cast<int*>(smem + 67584);

  const int tid = threadIdx.x;
  const int wv = tid >> 6, lane = tid & 63, quad = lane >> 4, c0 = lane & 15;
  const int t = tid >> 4, l = tid & 15;

  const int blk = blockIdx.x;
  const int b = blk / 63;
  const int p0 = (blk % 63) * 32;
  const int pA = p0 + t, pB = p0 + 16 + t;
  const int ii0 = idx_i[pA], jj0 = idx_j[pA];
  const int ii1 = idx_i[pB], jj1 = idx_j[pB];

  // ---- phase 1: A/B rows (both tiles) into registers, norms, combos ----
  float af0[8], bf0[8], af1[8], bf1[8];
  ld8(x + (size_t)(b * 64 + ii0) * 128 + l * 8, af0);
  ld8(x + (size_t)(b * 64 + jj0) * 128 + l * 8, bf0);
  ld8(x + (size_t)(b * 64 + ii1) * 128 + l * 8, af1);
  ld8(x + (size_t)(b * 64 + jj1) * 128 + l * 8, bf1);

  float sa0 = 0.f, sb0 = 0.f, sa1 = 0.f, sb1 = 0.f;
#pragma unroll
  for (int q = 0; q < 8; ++q) {
    sa0 = fmaf(af0[q], af0[q], sa0); sb0 = fmaf(bf0[q], bf0[q], sb0);
    sa1 = fmaf(af1[q], af1[q], sa1); sb1 = fmaf(bf1[q], bf1[q], sb1);
  }
#pragma unroll
  for (int m = 1; m < 16; m <<= 1) {
    sa0 += __shfl_xor(sa0, m); sb0 += __shfl_xor(sb0, m);
    sa1 += __shfl_xor(sa1, m); sb1 += __shfl_xor(sb1, m);
  }
  const float invA0 = 1.f / (sqrtf(sa0) + EPS), invB0 = 1.f / (sqrtf(sb0) + EPS);
  const float invA1 = 1.f / (sqrtf(sa1) + EPS), invB1 = 1.f / (sqrtf(sb1) + EPS);
  if (l == 0) {
    int pa = presence[b * 64 + ii0], pb = presence[b * 64 + jj0];
    sCombo[t] = pa ? (pb ? 0 : 1) : (pb ? 2 : 3);
    pa = presence[b * 64 + ii1]; pb = presence[b * 64 + jj1];
    sCombo[16 + t] = pa ? (pb ? 0 : 1) : (pb ? 2 : 3);
  }

  float ra0[8], rb0[8], ra1[8], rb1[8];   // only used by K=6/7 (round B)

  // ---- phase 2 round A: ops k = 0..3 -> H cols 0..255 ----
  phase2_op<0, 0, false>(t, l, wv, lane, quad, c0, af0, bf0, af1, bf1,
                         invA0, invB0, invA1, invB1, ra0, rb0, ra1, rb1,
                         Fh, Fl, Hh, Hl, W1H, W1L, ops_b1);
  phase2_op<1, 1, false>(t, l, wv, lane, quad, c0, af0, bf0, af1, bf1,
                         invA0, invB0, invA1, invB1, ra0, rb0, ra1, rb1,
                         Fh, Fl, Hh, Hl, W1H, W1L, ops_b1);
  phase2_op<2, 2, false>(t, l, wv, lane, quad, c0, af0, bf0, af1, bf1,
                         invA0, invB0, invA1, invB1, ra0, rb0, ra1, rb1,
                         Fh, Fl, Hh, Hl, W1H, W1L, ops_b1);
  phase2_op<3, 3, false>(t, l, wv, lane, quad, c0, af0, bf0, af1, bf1,
                         invA0, invB0, invA1, invB1, ra0, rb0, ra1, rb1,
                         Fh, Fl, Hh, Hl, W1H, W1L, ops_b1);
  __syncthreads();   // H (round A) complete

  // ---- phase 3 init + round A ----
  int comb0[4], comb1[4];
#pragma unroll
  for (int i = 0; i < 4; ++i) {
    comb0[i] = sCombo[quad * 4 + i];
    comb1[i] = sCombo[16 + quad * 4 + i];
  }
  ffrag u1[4], u2[4], v1[4], v2[4];
#pragma unroll
  for (int nt4 = 0; nt4 < 4; ++nt4) {
    int col = (wv * 4 + nt4) * 16 + c0;
#pragma unroll
    for (int i = 0; i < 4; ++i) {
      u1[nt4][i] = cbias[comb0[i] * 256 + col];
      v1[nt4][i] = cbias[comb1[i] * 256 + col];
    }
    u2[nt4] = ffrag{0.f, 0.f, 0.f, 0.f};
    v2[nt4] = ffrag{0.f, 0.f, 0.f, 0.f};
  }
  phase3_round(0, wv, lane, quad, c0, Hh, Hl, GpH, GpL, u1, u2, v1, v2);

  // ---- phase 2 round B: k=4 (+derived 5), 6, 7 -> H cols 0..255 again ----
#pragma unroll
  for (int q = 0; q < 8; ++q) {
    ra0[q] = __builtin_amdgcn_rcpf(af0[q] + EPS);
    rb0[q] = __builtin_amdgcn_rcpf(bf0[q] + EPS);
    ra1[q] = __builtin_amdgcn_rcpf(af1[q] + EPS);
    rb1[q] = __builtin_amdgcn_rcpf(bf1[q] + EPS);
  }
  phase2_op<4, 0, true>(t, l, wv, lane, quad, c0, af0, bf0, af1, bf1,
                        invA0, invB0, invA1, invB1, ra0, rb0, ra1, rb1,
                        Fh, Fl, Hh, Hl, W1H, W1L, ops_b1);
  phase2_op<6, 2, false>(t, l, wv, lane, quad, c0, af0, bf0, af1, bf1,
                         invA0, invB0, invA1, invB1, ra0, rb0, ra1, rb1,
                         Fh, Fl, Hh, Hl, W1H, W1L, ops_b1);
  phase2_op<7, 3, false>(t, l, wv, lane, quad, c0, af0, bf0, af1, bf1,
                         invA0, invB0, invA1, invB1, ra0, rb0, ra1, rb1,
                         Fh, Fl, Hh, Hl, W1H, W1L, ops_b1);
  __syncthreads();   // H (round B) complete

  phase3_round(1, wv, lane, quad, c0, Hh, Hl, GpH, GpL, u1, u2, v1, v2);

  // ---- write Hid (relu) into D (aliases F; F dead since round-B barrier) ----
#pragma unroll
  for (int nt4 = 0; nt4 < 4; ++nt4) {
    int col = (wv * 4 + nt4) * 16 + c0;
#pragma unroll
    for (int i = 0; i < 4; ++i) {
      short h, lo;
      split_bf(fmaxf(u1[nt4][i] + u2[nt4][i], 0.f), h, lo);
      Dh[quad * 4 + i][col] = (unsigned short)h; Dl[quad * 4 + i][col] = (unsigned short)lo;
      split_bf(fmaxf(v1[nt4][i] + v2[nt4][i], 0.f), h, lo);
      Dh[16 + quad * 4 + i][col] = (unsigned short)h; Dl[16 + quad * 4 + i][col] = (unsigned short)lo;
    }
  }
  __syncthreads();

  // ---- phase 4: out = Hid @ fus_W2 + fus_b2 ----
  ffrag o1[2], o2[2], q1[2], q2[2];
#pragma unroll
  for (int nt2 = 0; nt2 < 2; ++nt2) {
    float bias = fus_b2[(wv * 2 + nt2) * 16 + c0];
    o1[nt2] = ffrag{bias, bias, bias, bias};
    q1[nt2] = o1[nt2];
    o2[nt2] = ffrag{0.f, 0.f, 0.f, 0.f};
    q2[nt2] = o2[nt2];
  }
#pragma unroll
  for (int kk = 0; kk < 8; ++kk) {
    bfrag dh0 = *(const bfrag*)&Dh[c0][kk * 32 + quad * 8];
    bfrag dl0 = *(const bfrag*)&Dl[c0][kk * 32 + quad * 8];
    bfrag dh1 = *(const bfrag*)&Dh[16 + c0][kk * 32 + quad * 8];
    bfrag dl1 = *(const bfrag*)&Dl[16 + c0][kk * 32 + quad * 8];
#pragma unroll
    for (int nt2 = 0; nt2 < 2; ++nt2) {
      int off = (((wv * 2 + nt2) * 8 + kk) * 64 + lane) * 8;
      bfrag bh = *(const bfrag*)(W2H + off);
      bfrag bl = *(const bfrag*)(W2L + off);
      o1[nt2] = MFMA(dh0, bh, o1[nt2]);
      o2[nt2] = MFMA(dh0, bl, o2[nt2]);
      o2[nt2] = MFMA(dl0, bh, o2[nt2]);
      q1[nt2] = MFMA(dh1, bh, q1[nt2]);
      q2[nt2] = MFMA(dh1, bl, q2[nt2]);
      q2[nt2] = MFMA(dl1, bh, q2[nt2]);
    }
  }
#pragma unroll
  for (int nt2 = 0; nt2 < 2; ++nt2) {
    int col = (wv * 2 + nt2) * 16 + c0;
#pragma unroll
    for (int i = 0; i < 4; ++i) {
      int row = quad * 4 + i;
      out[(size_t)(b * 2016 + p0 + row) * 128 + col] = o1[nt2][i] + o2[nt2][i];
      out[(size_t)(b * 2016 + p0 + 16 + row) * 128 + col] = q1[nt2][i] + q2[nt2][i];
    }
  }
}

// ---------------------------------------------------------------------------
extern "C" void kernel_launch(void* const* d_in, const int* in_sizes, int n_in,
                              void* d_out, int out_size, void* d_ws, size_t ws_size,
                              hipStream_t stream) {
  const float* x        = (const float*)d_in[0];
  const int*   presence = (const int*)d_in[1];
  const int*   idx_i    = (const int*)d_in[2];
  const int*   idx_j    = (const int*)d_in[3];
  const float* ops_W1   = (const float*)d_in[4];
  const float* ops_b1   = (const float*)d_in[5];
  const float* ops_W2   = (const float*)d_in[6];
  const float* ops_b2   = (const float*)d_in[7];
  const float* pres_W1  = (const float*)d_in[8];
  const float* pres_b1  = (const float*)d_in[9];
  const float* pres_W2  = (const float*)d_in[10];
  const float* pres_b2  = (const float*)d_in[11];
  const float* fus_W1   = (const float*)d_in[12];
  const float* fus_b1   = (const float*)d_in[13];
  const float* fus_W2   = (const float*)d_in[14];
  const float* fus_b2   = (const float*)d_in[15];

  char* ws = (char*)d_ws;
  unsigned short* GpH = (unsigned short*)(ws);
  unsigned short* GpL = (unsigned short*)(ws + 262144);
  unsigned short* W1H = (unsigned short*)(ws + 524288);
  unsigned short* W1L = (unsigned short*)(ws + 655360);
  unsigned short* W2H = (unsigned short*)(ws + 786432);
  unsigned short* W2L = (unsigned short*)(ws + 851968);
  float*          CB  = (float*)(ws + 917504);

  prologue<<<564, 256, 0, stream>>>(ops_W1, ops_W2, ops_b2, pres_W1, pres_b1,
                                    pres_W2, pres_b2, fus_W1, fus_b1, fus_W2,
                                    GpH, GpL, W1H, W1L, W2H, W2L, CB);
  // 64 batches * 63 blocks, 32 tokens each = 129024 tokens
  drel_main<<<4032, 256, 0, stream>>>(x, presence, idx_i, idx_j, ops_b1, fus_b2,
                                      W1H, W1L, GpH, GpL, W2H, W2L, CB,
                                      (float*)d_out);
}